// Round 23
// baseline (38.989 us; speedup 1.0000x reference)
//
#include <hip/hip_runtime.h>
#include <math.h>

// LinearAttention: L=4096, B=4, H=8, D=Dv=64, fp32.
// out[l,b,h,e] = (phiQ[l,bh,:] . kv[bh,:,e]) / (phiQ[l,bh,:] . ksum[bh,:] + eps)
// kv[bh,d,e] = sum_l phiK[l,bh,d] * V[l,bh,e]   (GLOBAL sum)
// phi(x) = elu(x)+1
//
// R23 = 2 kernels. Reduce dispatch deleted: P2<NC> sums the NC partial slabs
// inline during staging. Both prior failure modes fixed simultaneously:
//  - template<NC> + #pragma unroll (R20 lesson: runtime loop serialized)
//  - P1 grid (bh, c) -> partials dirty in XCD bh%8; P2 block bh reads them
//    locally (R22 lesson: cross-XCD dirty lines are slow).
// P1 = R22-verbatim. Same summation order -> absmax must stay 2.441406e-4.

#define L_TOT 4096
#define NBH   32
#define ROWSTRIDE 2048
#define KVSZ  4160
#define EPS_  1e-6f

typedef short s16x8 __attribute__((ext_vector_type(8)));
typedef float f32x4 __attribute__((ext_vector_type(4)));

union FragU { unsigned int u[4]; s16x8 s; };

__device__ __forceinline__ float phi_(float x) {
    return x > 0.0f ? x + 1.0f : __expf(x);
}

__device__ __forceinline__ unsigned int bf16rn_(float x) {
    unsigned int u = __float_as_uint(x);
    return (u + 0x7FFFu + ((u >> 16) & 1u)) >> 16;    // bf16 bits in low16
}

__device__ __forceinline__ s16x8 frag_from_(const unsigned short* p) {
    uint2 a = *(const uint2*)p;
    uint2 b = *(const uint2*)(p + 4);
    FragU f;
    f.u[0] = a.x; f.u[1] = a.y; f.u[2] = b.x; f.u[3] = b.y;
    return f.s;
}

// ---------------- Pass 1 (R22-verbatim): MFMA partial, kvT, XCD-pinned -----
// grid = (NBH, nchunk): blockIdx.x = bh -> XCD = bh%8.
__global__ __launch_bounds__(256) void kv_partial_kernel(
    const float* __restrict__ K, const float* __restrict__ V,
    float* __restrict__ part, int Lc)
{
    __shared__ __align__(16) unsigned short kphi[64][40];
    __shared__ __align__(16) unsigned short vtr [64][40];
    __shared__ __align__(16) float xpose[64 * 65];

    const int tid  = threadIdx.x;
    const int w    = tid >> 6;
    const int lane = tid & 63;
    const int bh   = blockIdx.x;
    const int c    = blockIdx.y;
    const int l0c  = c * Lc;
    const int ntiles = Lc >> 5;

    const int sr = tid >> 4;
    const int sc = (tid & 15) * 4;
    const size_t bh_off = (size_t)bh * 64;

    const int ar = lane & 15;
    const int ag = lane >> 4;

    f32x4 acc[4];
    f32x4 aks = {0.f, 0.f, 0.f, 0.f};
    #pragma unroll
    for (int n = 0; n < 4; ++n) { f32x4 z = {0.f,0.f,0.f,0.f}; acc[n] = z; }

    FragU onesU;
    #pragma unroll
    for (int p = 0; p < 4; ++p) onesU.u[p] = 0x3F803F80u;
    const s16x8 ones = onesU.s;

    size_t gb = (size_t)(l0c + sr) * ROWSTRIDE + bh_off + sc;
    float4 ka = *(const float4*)(K + gb);
    float4 va = *(const float4*)(V + gb);
    float4 kb = *(const float4*)(K + gb + 16 * ROWSTRIDE);
    float4 vb = *(const float4*)(V + gb + 16 * ROWSTRIDE);

    for (int t = 0; t < ntiles; ++t) {
        {
            float kx[4] = {ka.x, ka.y, ka.z, ka.w};
            float vx[4] = {va.x, va.y, va.z, va.w};
            float ky[4] = {kb.x, kb.y, kb.z, kb.w};
            float vy[4] = {vb.x, vb.y, vb.z, vb.w};
            #pragma unroll
            for (int i = 0; i < 4; ++i) {
                kphi[sc + i][sr]      = (unsigned short)bf16rn_(phi_(kx[i]));
                kphi[sc + i][sr + 16] = (unsigned short)bf16rn_(phi_(ky[i]));
                vtr [sc + i][sr]      = (unsigned short)bf16rn_(vx[i]);
                vtr [sc + i][sr + 16] = (unsigned short)bf16rn_(vy[i]);
            }
        }
        __syncthreads();

        if (t + 1 < ntiles) {
            gb = (size_t)(l0c + (t + 1) * 32 + sr) * ROWSTRIDE + bh_off + sc;
            ka = *(const float4*)(K + gb);
            va = *(const float4*)(V + gb);
            kb = *(const float4*)(K + gb + 16 * ROWSTRIDE);
            vb = *(const float4*)(V + gb + 16 * ROWSTRIDE);
        }

        const s16x8 afrag = frag_from_(&kphi[w * 16 + ar][ag * 8]);

        #pragma unroll
        for (int nt = 0; nt < 4; ++nt) {
            const s16x8 bfrag = frag_from_(&vtr[nt * 16 + ar][ag * 8]);
            acc[nt] = __builtin_amdgcn_mfma_f32_16x16x32_bf16(afrag, bfrag, acc[nt], 0, 0, 0);
        }
        aks = __builtin_amdgcn_mfma_f32_16x16x32_bf16(afrag, ones, aks, 0, 0, 0);

        __syncthreads();
    }

    // epilogue: transpose via LDS, coalesced kvT stores
    #pragma unroll
    for (int nt = 0; nt < 4; ++nt) {
        #pragma unroll
        for (int r = 0; r < 4; ++r) {
            const int d_row = w * 16 + (lane >> 4) * 4 + r;
            const int e_col = nt * 16 + (lane & 15);
            xpose[d_row * 65 + e_col] = acc[nt][r];
        }
    }
    __syncthreads();

    float* pb = part + ((size_t)c * NBH + bh) * KVSZ;
    for (int u = tid; u < 1024; u += 256) {
        const int e  = u >> 4;
        const int jj = u & 15;
        float4 o;
        o.x = xpose[(4 * jj + 0) * 65 + e];
        o.y = xpose[(4 * jj + 1) * 65 + e];
        o.z = xpose[(4 * jj + 2) * 65 + e];
        o.w = xpose[(4 * jj + 3) * 65 + e];
        *(float4*)&pb[e * 64 + 4 * jj] = o;
    }
    if ((lane & 15) == 0) {
        #pragma unroll
        for (int r = 0; r < 4; ++r)
            pb[4096 + w * 16 + (lane >> 4) * 4 + r] = aks[r];
    }
}

// -------- Pass 2: bf16 MFMA + unrolled XCD-local inline reduction ----------
// grid = 512 (16 tg x 32 bh), block = 512. bid%32 = bh -> XCD = bh%8 matches
// P1's partials. Staging sums NC slabs (cc-ascending, unrolled) then splits
// to bf16 hi/lo. Rest = R16/R17-validated body.
template<int NC>
__global__ __launch_bounds__(512) void attn_out_kernel(
    const float* __restrict__ Q, const float* __restrict__ part,
    float* __restrict__ out)
{
    __shared__ __align__(16) unsigned short khi[80 * 72];
    __shared__ __align__(16) unsigned short klo[80 * 72];

    const int tid  = threadIdx.x;
    const int lane = tid & 63;
    const int w    = tid >> 6;
    const int bh   = blockIdx.x & 31;
    const int tg   = blockIdx.x >> 5;
    const int wt0  = tg * 256 + w * 32;

    for (int idx = tid; idx < 2080; idx += 512) {
        const int e = idx >> 5;            // 0..64 (row 64 = ksum)
        const int p = idx & 31;
        float sx = 0.f, sy = 0.f;
        #pragma unroll
        for (int cc = 0; cc < NC; ++cc) {
            const float2 v = *(const float2*)(part
                + ((size_t)cc * NBH + bh) * KVSZ + e * 64 + 2 * p);
            sx += v.x; sy += v.y;
        }
        unsigned int u0 = __float_as_uint(sx), u1 = __float_as_uint(sy);
        unsigned int hi = (u1 & 0xFFFF0000u) | (u0 >> 16);
        float r0 = sx - __uint_as_float(u0 & 0xFFFF0000u);
        float r1 = sy - __uint_as_float(u1 & 0xFFFF0000u);
        unsigned int lo = (bf16rn_(r1) << 16) | bf16rn_(r0);
        ((unsigned int*)(khi + e * 72))[p] = hi;
        ((unsigned int*)(klo + e * 72))[p] = lo;
    }
    for (int idx = tid; idx < 480; idx += 512) {   // zero rows 65..79
        const int e = 65 + (idx >> 5);
        const int p = idx & 31;
        ((unsigned int*)(khi + e * 72))[p] = 0u;
        ((unsigned int*)(klo + e * 72))[p] = 0u;
    }

    const int arow = lane & 15;
    const int agrp = lane >> 4;
    s16x8 ahi[2][2];
    #pragma unroll
    for (int m = 0; m < 2; ++m) {
        #pragma unroll
        for (int kc = 0; kc < 2; ++kc) {
            const float* qp = Q + (size_t)(wt0 + m*16 + arow) * ROWSTRIDE
                                + (size_t)bh * 64 + kc*32 + agrp*8;
            float4 qa = *(const float4*)qp;
            float4 qb = *(const float4*)(qp + 4);
            float x[8] = {qa.x,qa.y,qa.z,qa.w,qb.x,qb.y,qb.z,qb.w};
            FragU fh;
            #pragma unroll
            for (int p = 0; p < 4; ++p) {
                float p0 = phi_(x[2*p]), p1 = phi_(x[2*p+1]);
                fh.u[p] = (bf16rn_(p1) << 16) | bf16rn_(p0);
            }
            ahi[m][kc] = fh.s;
        }
    }
    __syncthreads();

    f32x4 acc[2][5];
    #pragma unroll
    for (int m = 0; m < 2; ++m) {
        #pragma unroll
        for (int n = 0; n < 5; ++n) { f32x4 z = {0.f,0.f,0.f,0.f}; acc[m][n] = z; }
    }

    #pragma unroll
    for (int nt = 0; nt < 5; ++nt) {
        #pragma unroll
        for (int kc = 0; kc < 2; ++kc) {
            const int off = (nt*16 + arow) * 72 + kc*32 + agrp*8;
            s16x8 bh_ = *(const s16x8*)(khi + off);
            s16x8 bl_ = *(const s16x8*)(klo + off);
            #pragma unroll
            for (int m = 0; m < 2; ++m) {
                acc[m][nt] = __builtin_amdgcn_mfma_f32_16x16x32_bf16(ahi[m][kc], bh_, acc[m][nt], 0, 0, 0);
                acc[m][nt] = __builtin_amdgcn_mfma_f32_16x16x32_bf16(ahi[m][kc], bl_, acc[m][nt], 0, 0, 0);
            }
        }
    }

    const int baddr = (lane & 48) << 2;
    float inv[2][4];
    #pragma unroll
    for (int m = 0; m < 2; ++m) {
        #pragma unroll
        for (int r = 0; r < 4; ++r) {
            float dv = __int_as_float(
                __builtin_amdgcn_ds_bpermute(baddr, __float_as_int(acc[m][4][r])));
            inv[m][r] = 1.0f / (dv + EPS_);
        }
    }

    #pragma unroll
    for (int m = 0; m < 2; ++m) {
        #pragma unroll
        for (int r = 0; r < 4; ++r) {
            const int t = wt0 + m*16 + (lane >> 4) * 4 + r;
            float* op = out + (size_t)t * ROWSTRIDE + (size_t)bh * 64 + (lane & 15);
            #pragma unroll
            for (int nt = 0; nt < 4; ++nt)
                op[nt * 16] = acc[m][nt][r] * inv[m][r];
        }
    }
}

extern "C" void kernel_launch(void* const* d_in, const int* in_sizes, int n_in,
                              void* d_out, int out_size, void* d_ws, size_t ws_size,
                              hipStream_t stream) {
    const float* Q = (const float*)d_in[0];
    const float* K = (const float*)d_in[1];
    const float* V = (const float*)d_in[2];
    float* outp = (float*)d_out;
    float* part = (float*)d_ws;

    const size_t slab = (size_t)NBH * KVSZ;          // 133120 floats = 532 KB

    int nchunk = 1;
    {
        const size_t cap = ws_size / (slab * sizeof(float));
        const int cand[4] = {16, 8, 4, 2};
        for (int i = 0; i < 4; ++i) {
            if (cap >= (size_t)cand[i]) { nchunk = cand[i]; break; }
        }
    }
    const int Lc = L_TOT / nchunk;

    hipLaunchKernelGGL(kv_partial_kernel, dim3(NBH, nchunk), dim3(256), 0, stream,
                       K, V, part, Lc);

    switch (nchunk) {
    case 16:
        hipLaunchKernelGGL((attn_out_kernel<16>), dim3(512), dim3(512), 0, stream,
                           Q, part, outp);
        break;
    case 8:
        hipLaunchKernelGGL((attn_out_kernel<8>),  dim3(512), dim3(512), 0, stream,
                           Q, part, outp);
        break;
    case 4:
        hipLaunchKernelGGL((attn_out_kernel<4>),  dim3(512), dim3(512), 0, stream,
                           Q, part, outp);
        break;
    case 2:
        hipLaunchKernelGGL((attn_out_kernel<2>),  dim3(512), dim3(512), 0, stream,
                           Q, part, outp);
        break;
    default:
        hipLaunchKernelGGL((attn_out_kernel<1>),  dim3(512), dim3(512), 0, stream,
                           Q, part, outp);
        break;
    }
}

// Round 24
// 33.893 us; speedup vs baseline: 1.1503x; 1.1503x over previous
//
#include <hip/hip_runtime.h>
#include <math.h>

// LinearAttention: L=4096, B=4, H=8, D=Dv=64, fp32.
// out[l,b,h,e] = (phiQ[l,bh,:] . kv[bh,:,e]) / (phiQ[l,bh,:] . ksum[bh,:] + eps)
// kv[bh,d,e] = sum_l phiK[l,bh,d] * V[l,bh,e]   (GLOBAL sum)
// phi(x) = elu(x)+1
//
// R24 = R22 (best, 34.9us) with P1 on 64-row K-tiles: barriers per block
// halve (16 -> 8). LDS pitch 68 u16 keeps writes 2-way (bank step 34%32=2)
// and uint2 frag alignment (136 B rows). MFMA order unchanged -> partials
// bit-identical. Reduce (XCD-pinned, unrolled) + P2 = R22-verbatim.

#define L_TOT 4096
#define NBH   32
#define ROWSTRIDE 2048
#define KVSZ  4160
#define EPS_  1e-6f

typedef short s16x8 __attribute__((ext_vector_type(8)));
typedef float f32x4 __attribute__((ext_vector_type(4)));

union FragU { unsigned int u[4]; s16x8 s; };

__device__ __forceinline__ float phi_(float x) {
    return x > 0.0f ? x + 1.0f : __expf(x);
}

__device__ __forceinline__ unsigned int bf16rn_(float x) {
    unsigned int u = __float_as_uint(x);
    return (u + 0x7FFFu + ((u >> 16) & 1u)) >> 16;    // bf16 bits in low16
}

__device__ __forceinline__ s16x8 frag_from_(const unsigned short* p) {
    uint2 a = *(const uint2*)p;
    uint2 b = *(const uint2*)(p + 4);
    FragU f;
    f.u[0] = a.x; f.u[1] = a.y; f.u[2] = b.x; f.u[3] = b.y;
    return f.s;
}

// ---------------- Pass 1: MFMA partial, kvT, XCD-pinned, 64-row tiles ------
// grid = (NBH, nchunk): blockIdx.x = bh -> XCD = bh%8.
__global__ __launch_bounds__(256) void kv_partial_kernel(
    const float* __restrict__ K, const float* __restrict__ V,
    float* __restrict__ part, int Lc)
{
    __shared__ __align__(16) unsigned short kphi[64][68];  // 8.7 KB phiK^T
    __shared__ __align__(16) unsigned short vtr [64][68];  // 8.7 KB V^T
    __shared__ __align__(16) float xpose[64 * 65];         // 16.6 KB

    const int tid  = threadIdx.x;
    const int w    = tid >> 6;
    const int lane = tid & 63;
    const int bh   = blockIdx.x;
    const int c    = blockIdx.y;
    const int l0c  = c * Lc;
    const int ntiles = Lc >> 6;            // Lc is a multiple of 64

    const int sr = tid >> 4;               // staging l 0..15 (+16,+32,+48)
    const int sc = (tid & 15) * 4;         // staging feature base (float4)
    const size_t bh_off = (size_t)bh * 64;

    const int ar = lane & 15;
    const int ag = lane >> 4;

    f32x4 acc[4];
    f32x4 aks = {0.f, 0.f, 0.f, 0.f};
    #pragma unroll
    for (int n = 0; n < 4; ++n) { f32x4 z = {0.f,0.f,0.f,0.f}; acc[n] = z; }

    FragU onesU;
    #pragma unroll
    for (int p = 0; p < 4; ++p) onesU.u[p] = 0x3F803F80u;
    const s16x8 ones = onesU.s;

    // prologue loads (tile 0): rows sr, sr+16, sr+32, sr+48
    float4 kr[4], vr[4];
    {
        size_t gb = (size_t)(l0c + sr) * ROWSTRIDE + bh_off + sc;
        #pragma unroll
        for (int q = 0; q < 4; ++q) {
            kr[q] = *(const float4*)(K + gb + (size_t)(q * 16) * ROWSTRIDE);
            vr[q] = *(const float4*)(V + gb + (size_t)(q * 16) * ROWSTRIDE);
        }
    }

    for (int t = 0; t < ntiles; ++t) {
        {
            #pragma unroll
            for (int q = 0; q < 4; ++q) {
                const int lrow = sr + q * 16;
                float kx[4] = {kr[q].x, kr[q].y, kr[q].z, kr[q].w};
                float vx[4] = {vr[q].x, vr[q].y, vr[q].z, vr[q].w};
                #pragma unroll
                for (int i = 0; i < 4; ++i) {
                    kphi[sc + i][lrow] = (unsigned short)bf16rn_(phi_(kx[i]));
                    vtr [sc + i][lrow] = (unsigned short)bf16rn_(vx[i]);
                }
            }
        }
        __syncthreads();

        if (t + 1 < ntiles) {
            size_t gb = (size_t)(l0c + (t + 1) * 64 + sr) * ROWSTRIDE + bh_off + sc;
            #pragma unroll
            for (int q = 0; q < 4; ++q) {
                kr[q] = *(const float4*)(K + gb + (size_t)(q * 16) * ROWSTRIDE);
                vr[q] = *(const float4*)(V + gb + (size_t)(q * 16) * ROWSTRIDE);
            }
        }

        #pragma unroll
        for (int kc = 0; kc < 2; ++kc) {
            const s16x8 afrag = frag_from_(&kphi[w * 16 + ar][kc * 32 + ag * 8]);
            #pragma unroll
            for (int nt = 0; nt < 4; ++nt) {
                const s16x8 bfrag = frag_from_(&vtr[nt * 16 + ar][kc * 32 + ag * 8]);
                acc[nt] = __builtin_amdgcn_mfma_f32_16x16x32_bf16(afrag, bfrag, acc[nt], 0, 0, 0);
            }
            aks = __builtin_amdgcn_mfma_f32_16x16x32_bf16(afrag, ones, aks, 0, 0, 0);
        }

        __syncthreads();
    }

    // epilogue: transpose via LDS, coalesced kvT stores
    #pragma unroll
    for (int nt = 0; nt < 4; ++nt) {
        #pragma unroll
        for (int r = 0; r < 4; ++r) {
            const int d_row = w * 16 + (lane >> 4) * 4 + r;
            const int e_col = nt * 16 + (lane & 15);
            xpose[d_row * 65 + e_col] = acc[nt][r];
        }
    }
    __syncthreads();

    float* pb = part + ((size_t)c * NBH + bh) * KVSZ;
    for (int u = tid; u < 1024; u += 256) {
        const int e  = u >> 4;
        const int jj = u & 15;
        float4 o;
        o.x = xpose[(4 * jj + 0) * 65 + e];
        o.y = xpose[(4 * jj + 1) * 65 + e];
        o.z = xpose[(4 * jj + 2) * 65 + e];
        o.w = xpose[(4 * jj + 3) * 65 + e];
        *(float4*)&pb[e * 64 + 4 * jj] = o;
    }
    if ((lane & 15) == 0) {
        #pragma unroll
        for (int r = 0; r < 4; ++r)
            pb[4096 + w * 16 + (lane >> 4) * 4 + r] = aks[r];
    }
}

// ------- reduce (R22-verbatim): XCD-pinned (bh, seg), template<NC> ---------
template<int NC>
__global__ __launch_bounds__(256) void kv_reduce_kernel(
    const float* __restrict__ part, float* __restrict__ fin)
{
    const int bh = blockIdx.x;
    const int r  = blockIdx.y * 256 + threadIdx.x;
    if (r >= KVSZ) return;

    float s = 0.f;
    #pragma unroll
    for (int cc = 0; cc < NC; ++cc)
        s += part[((size_t)cc * NBH + bh) * KVSZ + r];
    fin[(size_t)bh * KVSZ + r] = s;
}

// ---------------- Pass 2 (R22-verbatim): bf16 MFMA from fin ----------------
__global__ __launch_bounds__(512) void attn_out_kernel(
    const float* __restrict__ Q, const float* __restrict__ fin,
    float* __restrict__ out)
{
    __shared__ __align__(16) unsigned short khi[80 * 72];
    __shared__ __align__(16) unsigned short klo[80 * 72];

    const int tid  = threadIdx.x;
    const int lane = tid & 63;
    const int w    = tid >> 6;
    const int bh   = blockIdx.x & 31;
    const int tg   = blockIdx.x >> 5;
    const int wt0  = tg * 256 + w * 32;

    const float* __restrict__ fb = fin + (size_t)bh * KVSZ;

    for (int idx = tid; idx < 2080; idx += 512) {
        const int e = idx >> 5;
        const int p = idx & 31;
        const float2 x2 = *(const float2*)(fb + e * 64 + 2 * p);
        unsigned int u0 = __float_as_uint(x2.x), u1 = __float_as_uint(x2.y);
        unsigned int hi = (u1 & 0xFFFF0000u) | (u0 >> 16);
        float r0 = x2.x - __uint_as_float(u0 & 0xFFFF0000u);
        float r1 = x2.y - __uint_as_float(u1 & 0xFFFF0000u);
        unsigned int lo = (bf16rn_(r1) << 16) | bf16rn_(r0);
        ((unsigned int*)(khi + e * 72))[p] = hi;
        ((unsigned int*)(klo + e * 72))[p] = lo;
    }
    for (int idx = tid; idx < 480; idx += 512) {
        const int e = 65 + (idx >> 5);
        const int p = idx & 31;
        ((unsigned int*)(khi + e * 72))[p] = 0u;
        ((unsigned int*)(klo + e * 72))[p] = 0u;
    }

    const int arow = lane & 15;
    const int agrp = lane >> 4;
    s16x8 ahi[2][2];
    #pragma unroll
    for (int m = 0; m < 2; ++m) {
        #pragma unroll
        for (int kc = 0; kc < 2; ++kc) {
            const float* qp = Q + (size_t)(wt0 + m*16 + arow) * ROWSTRIDE
                                + (size_t)bh * 64 + kc*32 + agrp*8;
            float4 qa = *(const float4*)qp;
            float4 qb = *(const float4*)(qp + 4);
            float x[8] = {qa.x,qa.y,qa.z,qa.w,qb.x,qb.y,qb.z,qb.w};
            FragU fh;
            #pragma unroll
            for (int p = 0; p < 4; ++p) {
                float p0 = phi_(x[2*p]), p1 = phi_(x[2*p+1]);
                fh.u[p] = (bf16rn_(p1) << 16) | bf16rn_(p0);
            }
            ahi[m][kc] = fh.s;
        }
    }
    __syncthreads();

    f32x4 acc[2][5];
    #pragma unroll
    for (int m = 0; m < 2; ++m) {
        #pragma unroll
        for (int n = 0; n < 5; ++n) { f32x4 z = {0.f,0.f,0.f,0.f}; acc[m][n] = z; }
    }

    #pragma unroll
    for (int nt = 0; nt < 5; ++nt) {
        #pragma unroll
        for (int kc = 0; kc < 2; ++kc) {
            const int off = (nt*16 + arow) * 72 + kc*32 + agrp*8;
            s16x8 bh_ = *(const s16x8*)(khi + off);
            s16x8 bl_ = *(const s16x8*)(klo + off);
            #pragma unroll
            for (int m = 0; m < 2; ++m) {
                acc[m][nt] = __builtin_amdgcn_mfma_f32_16x16x32_bf16(ahi[m][kc], bh_, acc[m][nt], 0, 0, 0);
                acc[m][nt] = __builtin_amdgcn_mfma_f32_16x16x32_bf16(ahi[m][kc], bl_, acc[m][nt], 0, 0, 0);
            }
        }
    }

    const int baddr = (lane & 48) << 2;
    float inv[2][4];
    #pragma unroll
    for (int m = 0; m < 2; ++m) {
        #pragma unroll
        for (int r = 0; r < 4; ++r) {
            float dv = __int_as_float(
                __builtin_amdgcn_ds_bpermute(baddr, __float_as_int(acc[m][4][r])));
            inv[m][r] = 1.0f / (dv + EPS_);
        }
    }

    #pragma unroll
    for (int m = 0; m < 2; ++m) {
        #pragma unroll
        for (int r = 0; r < 4; ++r) {
            const int t = wt0 + m*16 + (lane >> 4) * 4 + r;
            float* op = out + (size_t)t * ROWSTRIDE + (size_t)bh * 64 + (lane & 15);
            #pragma unroll
            for (int nt = 0; nt < 4; ++nt)
                op[nt * 16] = acc[m][nt][r] * inv[m][r];
        }
    }
}

extern "C" void kernel_launch(void* const* d_in, const int* in_sizes, int n_in,
                              void* d_out, int out_size, void* d_ws, size_t ws_size,
                              hipStream_t stream) {
    const float* Q = (const float*)d_in[0];
    const float* K = (const float*)d_in[1];
    const float* V = (const float*)d_in[2];
    float* outp = (float*)d_out;
    float* ws   = (float*)d_ws;

    const size_t slab = (size_t)NBH * KVSZ;          // 133120 floats = 532 KB

    int nchunk = 1;
    {
        const size_t cap = ws_size / (slab * sizeof(float));
        const int cand[4] = {16, 8, 4, 2};
        for (int i = 0; i < 4; ++i) {
            if (cap >= (size_t)cand[i] + 1) { nchunk = cand[i]; break; }
        }
    }
    const int Lc = L_TOT / nchunk;                   // multiple of 64 for all cand

    float* fin  = ws;
    float* part = ws + slab;

    hipLaunchKernelGGL(kv_partial_kernel, dim3(NBH, nchunk), dim3(256), 0, stream,
                       K, V, part, Lc);

    const dim3 rgrid(NBH, (KVSZ + 255) / 256);       // (32, 17)
    switch (nchunk) {
    case 16:
        hipLaunchKernelGGL((kv_reduce_kernel<16>), rgrid, dim3(256), 0, stream, part, fin);
        break;
    case 8:
        hipLaunchKernelGGL((kv_reduce_kernel<8>),  rgrid, dim3(256), 0, stream, part, fin);
        break;
    case 4:
        hipLaunchKernelGGL((kv_reduce_kernel<4>),  rgrid, dim3(256), 0, stream, part, fin);
        break;
    case 2:
        hipLaunchKernelGGL((kv_reduce_kernel<2>),  rgrid, dim3(256), 0, stream, part, fin);
        break;
    default:
        hipLaunchKernelGGL((kv_reduce_kernel<1>),  rgrid, dim3(256), 0, stream, part, fin);
        break;
    }

    hipLaunchKernelGGL(attn_out_kernel, dim3(512), dim3(512), 0, stream,
                       Q, fin, outp);
}